// Round 1
// baseline (738.681 us; speedup 1.0000x reference)
//
#include <hip/hip_runtime.h>

typedef unsigned short u16;
typedef __bf16 bf16_t;
typedef bf16_t bf16x8 __attribute__((ext_vector_type(8)));
typedef float f32x4 __attribute__((ext_vector_type(4)));

#define LOG2E 1.4426950408889634f

__device__ __forceinline__ u16 f2bf(float f) {
  union { float f; unsigned u; } c; c.f = f;
  unsigned r = c.u + 0x7fffu + ((c.u >> 16) & 1u);
  return (u16)(r >> 16);
}
__device__ __forceinline__ float bf2f(u16 u) {
  union { unsigned u; float f; } c; c.u = ((unsigned)u) << 16;
  return c.f;
}

__device__ __forceinline__ void gload16(const void* g, void* l) {
  __builtin_amdgcn_global_load_lds(
      (const __attribute__((address_space(1))) unsigned int*)g,
      (__attribute__((address_space(3))) unsigned int*)l, 16, 0, 0);
}

#define MFMA16(a, b, c) __builtin_amdgcn_mfma_f32_16x16x32_bf16((a), (b), (c), 0, 0, 0)

// ---------------- prep kernels ----------------

__global__ __launch_bounds__(256) void k_convert_f32_bf16(const float* __restrict__ in,
                                                          u16* __restrict__ out, int n4) {
  int i = blockIdx.x * 256 + threadIdx.x;
  if (i >= n4) return;
  float4 v = ((const float4*)in)[i];
  ushort4 o;
  o.x = f2bf(v.x); o.y = f2bf(v.y); o.z = f2bf(v.z); o.w = f2bf(v.w);
  ((ushort4*)out)[i] = o;
}

// out[C][R] = bf16(in[R][C])
__global__ __launch_bounds__(256) void k_transpose_f32_bf16(const float* __restrict__ in,
                                                            u16* __restrict__ out, int R, int C) {
  __shared__ float tile[32][33];
  int tx = threadIdx.x, ty = threadIdx.y;
  int bx = blockIdx.x * 32, by = blockIdx.y * 32;
#pragma unroll
  for (int i = 0; i < 4; i++)
    tile[ty + i * 8][tx] = in[(size_t)(by + ty + i * 8) * C + bx + tx];
  __syncthreads();
#pragma unroll
  for (int i = 0; i < 4; i++)
    out[(size_t)(bx + ty + i * 8) * R + by + tx] = f2bf(tile[tx][ty + i * 8]);
}

__global__ __launch_bounds__(256) void k_transpose_bf16(const u16* __restrict__ in,
                                                        u16* __restrict__ out, int R, int C) {
  __shared__ u16 tile[32][33];
  int tx = threadIdx.x, ty = threadIdx.y;
  int bx = blockIdx.x * 32, by = blockIdx.y * 32;
#pragma unroll
  for (int i = 0; i < 4; i++)
    tile[ty + i * 8][tx] = in[(size_t)(by + ty + i * 8) * C + bx + tx];
  __syncthreads();
#pragma unroll
  for (int i = 0; i < 4; i++)
    out[(size_t)(bx + ty + i * 8) * R + by + tx] = tile[tx][ty + i * 8];
}

// ---------------- RoPE (in place, bf16) ----------------
// x: [4096 rows][width], head layout h*256 + d, pairs (d, d+128)
__global__ __launch_bounds__(256) void k_rope(u16* __restrict__ x, const int* __restrict__ pos,
                                              int nh_mask, int nh_shift, int width) {
  int idx = blockIdx.x * 256 + threadIdx.x;
  int i = idx & 127;
  int h = (idx >> 7) & nh_mask;
  int row = idx >> (7 + nh_shift);
  int p = pos[row];  // row == b*2048 + s, pos flat [B*S]
  float f = (float)p * exp2f((float)i * (-13.287712379549449f / 128.f));
  float sn, cs;
  sincosf(f, &sn, &cs);
  size_t base = (size_t)row * width + h * 256 + i;
  float x1 = bf2f(x[base]), x2 = bf2f(x[base + 128]);
  x[base] = f2bf(x1 * cs - x2 * sn);
  x[base + 128] = f2bf(x2 * cs + x1 * sn);
}

// ---------------- GEMM: C[M][N] = A[M][K] * Bt[N][K]^T  (m97-style) ----------------

template <int OUT_BF16>
__global__ __launch_bounds__(256) void k_gemm_bt(const u16* __restrict__ A,
                                                 const u16* __restrict__ Bt,
                                                 void* __restrict__ C, int M, int N, int K) {
  __shared__ u16 As[128 * 64];
  __shared__ u16 Bs[128 * 64];
  const int tid = threadIdx.x;
  const int lane = tid & 63;
  const int w = tid >> 6;
  const int l15 = lane & 15, l4 = lane >> 4;
  const int wr = w >> 1, wc = w & 1;
  const int bx = blockIdx.x, by = blockIdx.y;

  f32x4 acc[4][4];
#pragma unroll
  for (int a = 0; a < 4; a++)
#pragma unroll
    for (int b2 = 0; b2 < 4; b2++) acc[a][b2] = (f32x4){0.f, 0.f, 0.f, 0.f};

  const u16* Abase = A + (size_t)by * 128 * K;
  const u16* Bbase = Bt + (size_t)bx * 128 * K;

  for (int kk = 0; kk < K; kk += 64) {
    __syncthreads();
#pragma unroll
    for (int j = 0; j < 4; j++) {
      int ci = w * 256 + j * 64 + lane;
      int row = ci >> 3, c = ci & 7;
      gload16(Abase + (size_t)row * K + kk + c * 8, (char*)As + ci * 16);
      gload16(Bbase + (size_t)row * K + kk + c * 8, (char*)Bs + ci * 16);
    }
    __syncthreads();
#pragma unroll
    for (int kc = 0; kc < 2; kc++) {
      int kb = kc * 64 + l4 * 16;
      bf16x8 av[4], bv[4];
#pragma unroll
      for (int mt = 0; mt < 4; mt++)
        av[mt] = *(const bf16x8*)((const char*)As + (wr * 64 + mt * 16 + l15) * 128 + kb);
#pragma unroll
      for (int nt = 0; nt < 4; nt++)
        bv[nt] = *(const bf16x8*)((const char*)Bs + (wc * 64 + nt * 16 + l15) * 128 + kb);
#pragma unroll
      for (int mt = 0; mt < 4; mt++)
#pragma unroll
        for (int nt = 0; nt < 4; nt++) acc[mt][nt] = MFMA16(av[mt], bv[nt], acc[mt][nt]);
    }
  }
#pragma unroll
  for (int mt = 0; mt < 4; mt++) {
#pragma unroll
    for (int nt = 0; nt < 4; nt++) {
      int col = bx * 128 + wc * 64 + nt * 16 + l15;
#pragma unroll
      for (int r = 0; r < 4; r++) {
        int row = by * 128 + wr * 64 + mt * 16 + l4 * 4 + r;
        if (OUT_BF16)
          ((u16*)C)[(size_t)row * N + col] = f2bf(acc[mt][nt][r]);
        else
          ((float*)C)[(size_t)row * N + col] = acc[mt][nt][r];
      }
    }
  }
}

// ---------------- flash attention ----------------
// Q: [4096][4096] bf16 (rope'd), Kb: [4096][1024] bf16 (rope'd), Vt: [1024][4096] bf16
// AO: [4096][4096] bf16. grid (S/64=32, B*H=32), 256 threads.
__global__ __launch_bounds__(256) void k_attn(const u16* __restrict__ Q,
                                              const u16* __restrict__ Kb,
                                              const u16* __restrict__ Vt,
                                              u16* __restrict__ AO) {
  extern __shared__ char smem[];
  u16* Ks = (u16*)smem;                  // [64][256] bf16, chunk-swizzled (32 KB)
  u16* Vs = (u16*)(smem + 32768);        // [256][64] bf16, chunk-swizzled (32 KB)
  u16* Ps = (u16*)(smem + 65536);        // 4 waves x [16][64] bf16, swizzled (8 KB)

  const int tid = threadIdx.x, lane = tid & 63, w = tid >> 6;
  const int l15 = lane & 15, l4 = lane >> 4;
  const int qb = blockIdx.x, bh = blockIdx.y;
  const int b = bh >> 4, h = bh & 15, kv = h >> 2;

  bf16x8 q[8];
  {
    const u16* qp = Q + (size_t)(b * 2048 + qb * 64 + w * 16 + l15) * 4096 + h * 256 + l4 * 8;
#pragma unroll
    for (int kc = 0; kc < 8; kc++) q[kc] = *(const bf16x8*)(qp + kc * 32);
  }
  f32x4 o[16];
#pragma unroll
  for (int nt = 0; nt < 16; nt++) o[nt] = (f32x4){0.f, 0.f, 0.f, 0.f};
  float mrow[4] = {-3e38f, -3e38f, -3e38f, -3e38f};
  float lrow[4] = {0.f, 0.f, 0.f, 0.f};

  for (int t = 0; t <= qb; ++t) {
    __syncthreads();
    // stage K tile [64][256]: 2048 16B-chunks, source pre-swizzled (chunk ^= row&7)
#pragma unroll
    for (int j = 0; j < 8; j++) {
      int ci = w * 512 + j * 64 + lane;
      int row = ci >> 5, c = ci & 31;
      int cg = (c & 24) | ((c ^ row) & 7);
      gload16(Kb + (size_t)(b * 2048 + t * 64 + row) * 1024 + kv * 256 + cg * 8,
              (char*)Ks + ci * 16);
    }
    // stage V^T tile [256][64]
#pragma unroll
    for (int j = 0; j < 8; j++) {
      int ci = w * 512 + j * 64 + lane;
      int row = ci >> 3, c = ci & 7;
      int cg = (c ^ row) & 7;
      gload16(Vt + (size_t)(kv * 256 + row) * 4096 + b * 2048 + t * 64 + cg * 8,
              (char*)Vs + ci * 16);
    }
    __syncthreads();

    // QK^T : S[16 q][64 kv]
    f32x4 sa[4];
#pragma unroll
    for (int nt = 0; nt < 4; nt++) sa[nt] = (f32x4){0.f, 0.f, 0.f, 0.f};
#pragma unroll
    for (int kc = 0; kc < 8; kc++) {
#pragma unroll
      for (int nt = 0; nt < 4; nt++) {
        int row = nt * 16 + l15;
        int ch = kc * 4 + l4;
        int cs = (ch & 24) | ((ch ^ row) & 7);
        bf16x8 kf = *(const bf16x8*)((const char*)Ks + row * 512 + cs * 16);
        sa[nt] = MFMA16(q[kc], kf, sa[nt]);
      }
    }

    // online softmax
    float x[4][4];
#pragma unroll
    for (int nt = 0; nt < 4; nt++)
#pragma unroll
      for (int r = 0; r < 4; r++) x[nt][r] = sa[nt][r] * 0.0625f;
    if (t == qb) {
#pragma unroll
      for (int nt = 0; nt < 4; nt++) {
        int col = t * 64 + nt * 16 + l15;
#pragma unroll
        for (int r = 0; r < 4; r++) {
          int rowg = qb * 64 + w * 16 + l4 * 4 + r;
          if (col > rowg) x[nt][r] = -1e30f;
        }
      }
    }
    float alpha[4], p[4][4];
#pragma unroll
    for (int r = 0; r < 4; r++) {
      float mx = fmaxf(fmaxf(x[0][r], x[1][r]), fmaxf(x[2][r], x[3][r]));
      mx = fmaxf(mx, __shfl_xor(mx, 1));
      mx = fmaxf(mx, __shfl_xor(mx, 2));
      mx = fmaxf(mx, __shfl_xor(mx, 4));
      mx = fmaxf(mx, __shfl_xor(mx, 8));
      float mn = fmaxf(mrow[r], mx);
      float al = exp2f((mrow[r] - mn) * LOG2E);
      mrow[r] = mn;
      float sum = 0.f;
#pragma unroll
      for (int nt = 0; nt < 4; nt++) {
        p[nt][r] = exp2f((x[nt][r] - mn) * LOG2E);
        sum += p[nt][r];
      }
      sum += __shfl_xor(sum, 1);
      sum += __shfl_xor(sum, 2);
      sum += __shfl_xor(sum, 4);
      sum += __shfl_xor(sum, 8);
      lrow[r] = lrow[r] * al + sum;
      alpha[r] = al;
    }
#pragma unroll
    for (int nt = 0; nt < 16; nt++) {
      o[nt][0] *= alpha[0]; o[nt][1] *= alpha[1];
      o[nt][2] *= alpha[2]; o[nt][3] *= alpha[3];
    }
    // P -> per-wave LDS (swizzled), then PV
    u16* pw = Ps + w * 1024;
#pragma unroll
    for (int nt = 0; nt < 4; nt++) {
#pragma unroll
      for (int r = 0; r < 4; r++) {
        int prow = l4 * 4 + r;
        int colb = nt * 32 + l15 * 2;
        int ch = colb >> 4;
        int cs = ch ^ (prow & 7);
        *(u16*)((char*)pw + prow * 128 + cs * 16 + (colb & 15)) = f2bf(p[nt][r]);
      }
    }
#pragma unroll
    for (int kc = 0; kc < 2; kc++) {
      int pch = kc * 4 + l4;
      int pcs = pch ^ (l15 & 7);
      bf16x8 pa = *(const bf16x8*)((const char*)pw + l15 * 128 + pcs * 16);
#pragma unroll
      for (int nt = 0; nt < 16; nt++) {
        int vrow = nt * 16 + l15;
        int vch = kc * 4 + l4;
        int vcs = vch ^ (vrow & 7);
        bf16x8 vf = *(const bf16x8*)((const char*)Vs + vrow * 128 + vcs * 16);
        o[nt] = MFMA16(pa, vf, o[nt]);
      }
    }
  }
#pragma unroll
  for (int r = 0; r < 4; r++) lrow[r] = 1.f / lrow[r];
  int rowg = b * 2048 + qb * 64 + w * 16 + l4 * 4;
#pragma unroll
  for (int nt = 0; nt < 16; nt++)
#pragma unroll
    for (int r = 0; r < 4; r++)
      AO[(size_t)(rowg + r) * 4096 + h * 256 + nt * 16 + l15] = f2bf(o[nt][r] * lrow[r]);
}

// ---------------- host ----------------

// ws layout (bytes). AO aliases Xb+Wqt (dead by then). Needs 112 MB of ws.
#define OFF_XB   0u
#define OFF_WQT  16777216u
#define OFF_WKT  33554432u
#define OFF_WVT  37748736u
#define OFF_WOT  41943040u
#define OFF_QB   58720256u
#define OFF_KB   92274688u
#define OFF_VB   100663296u
#define OFF_VT   109051904u
#define OFF_AO   0u

extern "C" void kernel_launch(void* const* d_in, const int* in_sizes, int n_in,
                              void* d_out, int out_size, void* d_ws, size_t ws_size,
                              hipStream_t stream) {
  const float* hs = (const float*)d_in[0];
  const int* pos = (const int*)d_in[1];
  const float* wq = (const float*)d_in[2];
  const float* wk = (const float*)d_in[3];
  const float* wv = (const float*)d_in[4];
  const float* wo = (const float*)d_in[5];
  float* out = (float*)d_out;
  char* ws = (char*)d_ws;

  u16* Xb  = (u16*)(ws + OFF_XB);
  u16* Wqt = (u16*)(ws + OFF_WQT);
  u16* Wkt = (u16*)(ws + OFF_WKT);
  u16* Wvt = (u16*)(ws + OFF_WVT);
  u16* Wot = (u16*)(ws + OFF_WOT);
  u16* Qb  = (u16*)(ws + OFF_QB);
  u16* Kb  = (u16*)(ws + OFF_KB);
  u16* Vb  = (u16*)(ws + OFF_VB);
  u16* Vt  = (u16*)(ws + OFF_VT);
  u16* AO  = (u16*)(ws + OFF_AO);

  dim3 tb(32, 8);

  // prep: convert + transposes
  k_convert_f32_bf16<<<8192, 256, 0, stream>>>(hs, Xb, 2097152);
  k_transpose_f32_bf16<<<dim3(128, 64), tb, 0, stream>>>(wq, Wqt, 2048, 4096);
  k_transpose_f32_bf16<<<dim3(32, 64), tb, 0, stream>>>(wk, Wkt, 2048, 1024);
  k_transpose_f32_bf16<<<dim3(32, 64), tb, 0, stream>>>(wv, Wvt, 2048, 1024);
  k_transpose_f32_bf16<<<dim3(64, 128), tb, 0, stream>>>(wo, Wot, 4096, 2048);

  // QKV projections
  k_gemm_bt<1><<<dim3(32, 32), 256, 0, stream>>>(Xb, Wqt, Qb, 4096, 4096, 2048);
  k_gemm_bt<1><<<dim3(8, 32), 256, 0, stream>>>(Xb, Wkt, Kb, 4096, 1024, 2048);
  k_gemm_bt<1><<<dim3(8, 32), 256, 0, stream>>>(Xb, Wvt, Vb, 4096, 1024, 2048);

  // RoPE on Q and K
  k_rope<<<32768, 256, 0, stream>>>(Qb, pos, 15, 4, 4096);
  k_rope<<<8192, 256, 0, stream>>>(Kb, pos, 3, 2, 1024);

  // V^T for attention PV operand
  k_transpose_bf16<<<dim3(32, 128), tb, 0, stream>>>(Vb, Vt, 4096, 1024);

  // flash attention
  (void)hipFuncSetAttribute((const void*)k_attn, hipFuncAttributeMaxDynamicSharedMemorySize, 73728);
  k_attn<<<dim3(32, 32), 256, 73728, stream>>>(Qb, Kb, Vt, AO);

  // output projection (fp32 out)
  k_gemm_bt<0><<<dim3(16, 32), 256, 0, stream>>>(AO, Wot, out, 4096, 2048, 4096);
}

// Round 2
// 566.824 us; speedup vs baseline: 1.3032x; 1.3032x over previous
//
#include <hip/hip_runtime.h>

typedef unsigned short u16;
typedef __bf16 bf16_t;
typedef bf16_t bf16x8 __attribute__((ext_vector_type(8)));
typedef float f32x4 __attribute__((ext_vector_type(4)));

#define LOG2E 1.4426950408889634f

__device__ __forceinline__ u16 f2bf(float f) {
  union { float f; unsigned u; } c; c.f = f;
  unsigned r = c.u + 0x7fffu + ((c.u >> 16) & 1u);
  return (u16)(r >> 16);
}
__device__ __forceinline__ float bf2f(u16 u) {
  union { unsigned u; float f; } c; c.u = ((unsigned)u) << 16;
  return c.f;
}

__device__ __forceinline__ void gload16(const void* g, void* l) {
  __builtin_amdgcn_global_load_lds(
      (const __attribute__((address_space(1))) unsigned int*)g,
      (__attribute__((address_space(3))) unsigned int*)l, 16, 0, 0);
}

#define MFMA16(a, b, c) __builtin_amdgcn_mfma_f32_16x16x32_bf16((a), (b), (c), 0, 0, 0)

// ---------------- prep kernels ----------------

__global__ __launch_bounds__(256) void k_convert_f32_bf16(const float* __restrict__ in,
                                                          u16* __restrict__ out, int n4) {
  int i = blockIdx.x * 256 + threadIdx.x;
  if (i >= n4) return;
  float4 v = ((const float4*)in)[i];
  ushort4 o;
  o.x = f2bf(v.x); o.y = f2bf(v.y); o.z = f2bf(v.z); o.w = f2bf(v.w);
  ((ushort4*)out)[i] = o;
}

// out[C][R] = bf16(in[R][C])
__global__ __launch_bounds__(256) void k_transpose_f32_bf16(const float* __restrict__ in,
                                                            u16* __restrict__ out, int R, int C) {
  __shared__ float tile[32][33];
  int tx = threadIdx.x, ty = threadIdx.y;
  int bx = blockIdx.x * 32, by = blockIdx.y * 32;
#pragma unroll
  for (int i = 0; i < 4; i++)
    tile[ty + i * 8][tx] = in[(size_t)(by + ty + i * 8) * C + bx + tx];
  __syncthreads();
#pragma unroll
  for (int i = 0; i < 4; i++)
    out[(size_t)(bx + ty + i * 8) * R + by + tx] = f2bf(tile[tx][ty + i * 8]);
}

__global__ __launch_bounds__(256) void k_transpose_bf16(const u16* __restrict__ in,
                                                        u16* __restrict__ out, int R, int C) {
  __shared__ u16 tile[32][33];
  int tx = threadIdx.x, ty = threadIdx.y;
  int bx = blockIdx.x * 32, by = blockIdx.y * 32;
#pragma unroll
  for (int i = 0; i < 4; i++)
    tile[ty + i * 8][tx] = in[(size_t)(by + ty + i * 8) * C + bx + tx];
  __syncthreads();
#pragma unroll
  for (int i = 0; i < 4; i++)
    out[(size_t)(bx + ty + i * 8) * R + by + tx] = tile[tx][ty + i * 8];
}

// ---------------- RoPE (in place, bf16) ----------------
__global__ __launch_bounds__(256) void k_rope(u16* __restrict__ x, const int* __restrict__ pos,
                                              int nh_mask, int nh_shift, int width) {
  int idx = blockIdx.x * 256 + threadIdx.x;
  int i = idx & 127;
  int h = (idx >> 7) & nh_mask;
  int row = idx >> (7 + nh_shift);
  int p = pos[row];
  float f = (float)p * exp2f((float)i * (-13.287712379549449f / 128.f));
  float sn, cs;
  sincosf(f, &sn, &cs);
  size_t base = (size_t)row * width + h * 256 + i;
  float x1 = bf2f(x[base]), x2 = bf2f(x[base + 128]);
  x[base] = f2bf(x1 * cs - x2 * sn);
  x[base + 128] = f2bf(x2 * cs + x1 * sn);
}

// ---------------- GEMM: C[M][N] = A[M][K] * Bt[N][K]^T  (m97-style) ----------------

template <int OUT_BF16>
__global__ __launch_bounds__(256) void k_gemm_bt(const u16* __restrict__ A,
                                                 const u16* __restrict__ Bt,
                                                 void* __restrict__ C, int M, int N, int K) {
  __shared__ u16 As[128 * 64];
  __shared__ u16 Bs[128 * 64];
  const int tid = threadIdx.x;
  const int lane = tid & 63;
  const int w = tid >> 6;
  const int l15 = lane & 15, l4 = lane >> 4;
  const int wr = w >> 1, wc = w & 1;
  const int bx = blockIdx.x, by = blockIdx.y;

  f32x4 acc[4][4];
#pragma unroll
  for (int a = 0; a < 4; a++)
#pragma unroll
    for (int b2 = 0; b2 < 4; b2++) acc[a][b2] = (f32x4){0.f, 0.f, 0.f, 0.f};

  const u16* Abase = A + (size_t)by * 128 * K;
  const u16* Bbase = Bt + (size_t)bx * 128 * K;

  for (int kk = 0; kk < K; kk += 64) {
    __syncthreads();
#pragma unroll
    for (int j = 0; j < 4; j++) {
      int ci = w * 256 + j * 64 + lane;
      int row = ci >> 3, c = ci & 7;
      gload16(Abase + (size_t)row * K + kk + c * 8, (char*)As + ci * 16);
      gload16(Bbase + (size_t)row * K + kk + c * 8, (char*)Bs + ci * 16);
    }
    __syncthreads();
#pragma unroll
    for (int kc = 0; kc < 2; kc++) {
      int kb = kc * 64 + l4 * 16;
      bf16x8 av[4], bv[4];
#pragma unroll
      for (int mt = 0; mt < 4; mt++)
        av[mt] = *(const bf16x8*)((const char*)As + (wr * 64 + mt * 16 + l15) * 128 + kb);
#pragma unroll
      for (int nt = 0; nt < 4; nt++)
        bv[nt] = *(const bf16x8*)((const char*)Bs + (wc * 64 + nt * 16 + l15) * 128 + kb);
#pragma unroll
      for (int mt = 0; mt < 4; mt++)
#pragma unroll
        for (int nt = 0; nt < 4; nt++) acc[mt][nt] = MFMA16(av[mt], bv[nt], acc[mt][nt]);
    }
  }
#pragma unroll
  for (int mt = 0; mt < 4; mt++) {
#pragma unroll
    for (int nt = 0; nt < 4; nt++) {
      int col = bx * 128 + wc * 64 + nt * 16 + l15;
#pragma unroll
      for (int r = 0; r < 4; r++) {
        int row = by * 128 + wr * 64 + mt * 16 + l4 * 4 + r;
        if (OUT_BF16)
          ((u16*)C)[(size_t)row * N + col] = f2bf(acc[mt][nt][r]);
        else
          ((float*)C)[(size_t)row * N + col] = acc[mt][nt][r];
      }
    }
  }
}

// ---------------- flash attention ----------------
// 512 threads (8 waves), QBLK=128 (16 q-rows/wave), KVBLK=64, double-buffered K/V.
// LDS: K0 32K | K1 32K | V0 32K | V1 32K | P 16K = 144 KB.
// grid (S/128=16, B*H=32); qb reversed so heavy blocks launch first.
__global__ __launch_bounds__(512) void k_attn(const u16* __restrict__ Q,
                                              const u16* __restrict__ Kb,
                                              const u16* __restrict__ Vt,
                                              u16* __restrict__ AO) {
  extern __shared__ char smem[];
  char* Kc = smem;
  char* Kn = smem + 32768;
  char* Vc = smem + 65536;
  char* Vn = smem + 98304;
  u16* Ps = (u16*)(smem + 131072);

  const int tid = threadIdx.x, lane = tid & 63, w = tid >> 6;
  const int l15 = lane & 15, l4 = lane >> 4;
  const int qb = (int)gridDim.x - 1 - (int)blockIdx.x;
  const int bh = blockIdx.y;
  const int b = bh >> 4, h = bh & 15, kv = h >> 2;

  bf16x8 q[8];
  {
    const u16* qp = Q + (size_t)(b * 2048 + qb * 128 + w * 16 + l15) * 4096 + h * 256 + l4 * 8;
#pragma unroll
    for (int kc = 0; kc < 8; kc++) q[kc] = *(const bf16x8*)(qp + kc * 32);
  }
  f32x4 o[16];
#pragma unroll
  for (int nt = 0; nt < 16; nt++) o[nt] = (f32x4){0.f, 0.f, 0.f, 0.f};
  float mrow[4] = {-3e38f, -3e38f, -3e38f, -3e38f};
  float lrow[4] = {0.f, 0.f, 0.f, 0.f};

  const int tmax = 2 * qb + 1;
  const int rowg0 = qb * 128 + w * 16;  // wave's first q-row (sequence-local)

  // ---- staging helper: K tile [64][256] + V^T tile [256][64], chunk-swizzled ----
  auto STAGE = [&](int t, char* Kd, char* Vd) {
#pragma unroll
    for (int j = 0; j < 4; j++) {
      int ci = j * 512 + tid;
      int row = ci >> 5, c = ci & 31;
      int cg = (c & 24) | ((c ^ row) & 7);
      gload16(Kb + (size_t)(b * 2048 + t * 64 + row) * 1024 + kv * 256 + cg * 8, Kd + ci * 16);
    }
#pragma unroll
    for (int j = 0; j < 4; j++) {
      int ci = j * 512 + tid;
      int row = ci >> 3, c = ci & 7;
      int cg = (c ^ row) & 7;
      gload16(Vt + (size_t)(kv * 256 + row) * 4096 + b * 2048 + t * 64 + cg * 8, Vd + ci * 16);
    }
  };

  STAGE(0, Kc, Vc);
  __syncthreads();  // drains vmcnt(0): tile 0 ready

  for (int t = 0; t <= tmax; ++t) {
    if (t < tmax) STAGE(t + 1, Kn, Vn);  // async prefetch; drained by end-of-iter barrier

    if (t * 64 <= rowg0 + 15) {  // wave has at least one unmasked col in this tile
      // ---- QK^T : S[16 q][64 kv] ----
      f32x4 sa[4];
#pragma unroll
      for (int nt = 0; nt < 4; nt++) sa[nt] = (f32x4){0.f, 0.f, 0.f, 0.f};
#pragma unroll
      for (int kc = 0; kc < 8; kc++) {
#pragma unroll
        for (int nt = 0; nt < 4; nt++) {
          int row = nt * 16 + l15;
          int ch = kc * 4 + l4;
          int cs = (ch & 24) | ((ch ^ row) & 7);
          bf16x8 kf = *(const bf16x8*)(Kc + row * 512 + cs * 16);
          sa[nt] = MFMA16(q[kc], kf, sa[nt]);
        }
      }

      // ---- scale + causal mask ----
      float x[4][4];
#pragma unroll
      for (int nt = 0; nt < 4; nt++)
#pragma unroll
        for (int r = 0; r < 4; r++) x[nt][r] = sa[nt][r] * 0.0625f;
      if (t * 64 + 63 > rowg0) {  // diagonal tile for this wave
#pragma unroll
        for (int nt = 0; nt < 4; nt++) {
          int col = t * 64 + nt * 16 + l15;
#pragma unroll
          for (int r = 0; r < 4; r++) {
            int rowq = rowg0 + l4 * 4 + r;
            if (col > rowq) x[nt][r] = -1e30f;
          }
        }
      }

      // ---- online softmax with defer-max (THR=8) ----
      float mx[4];
      bool need = false;
#pragma unroll
      for (int r = 0; r < 4; r++) {
        float m0 = fmaxf(fmaxf(x[0][r], x[1][r]), fmaxf(x[2][r], x[3][r]));
        m0 = fmaxf(m0, __shfl_xor(m0, 1));
        m0 = fmaxf(m0, __shfl_xor(m0, 2));
        m0 = fmaxf(m0, __shfl_xor(m0, 4));
        m0 = fmaxf(m0, __shfl_xor(m0, 8));
        mx[r] = m0;
        need = need || (m0 > mrow[r] + 8.f);
      }
      if (__any(need)) {
        float alpha[4];
#pragma unroll
        for (int r = 0; r < 4; r++) {
          float mn = fmaxf(mrow[r], mx[r]);
          alpha[r] = exp2f((mrow[r] - mn) * LOG2E);
          mrow[r] = mn;
          lrow[r] *= alpha[r];
        }
#pragma unroll
        for (int nt = 0; nt < 16; nt++) {
          o[nt][0] *= alpha[0]; o[nt][1] *= alpha[1];
          o[nt][2] *= alpha[2]; o[nt][3] *= alpha[3];
        }
      }
      float p[4][4];
#pragma unroll
      for (int r = 0; r < 4; r++) {
        float sum = 0.f;
#pragma unroll
        for (int nt = 0; nt < 4; nt++) {
          p[nt][r] = exp2f((x[nt][r] - mrow[r]) * LOG2E);
          sum += p[nt][r];
        }
        sum += __shfl_xor(sum, 1);
        sum += __shfl_xor(sum, 2);
        sum += __shfl_xor(sum, 4);
        sum += __shfl_xor(sum, 8);
        lrow[r] += sum;
      }

      // ---- P -> per-wave LDS (swizzled) ----
      u16* pw = Ps + w * 1024;
#pragma unroll
      for (int nt = 0; nt < 4; nt++) {
#pragma unroll
        for (int r = 0; r < 4; r++) {
          int prow = l4 * 4 + r;
          int colb = nt * 32 + l15 * 2;
          int ch = colb >> 4;
          int cs = ch ^ (prow & 7);
          *(u16*)((char*)pw + prow * 128 + cs * 16 + (colb & 15)) = f2bf(p[nt][r]);
        }
      }

      // ---- PV ----
#pragma unroll
      for (int kc = 0; kc < 2; kc++) {
        int pch = kc * 4 + l4;
        int pcs = pch ^ (l15 & 7);
        bf16x8 pa = *(const bf16x8*)((const char*)pw + l15 * 128 + pcs * 16);
#pragma unroll
        for (int nt = 0; nt < 16; nt++) {
          int vrow = nt * 16 + l15;
          int vch = kc * 4 + l4;
          int vcs = vch ^ (vrow & 7);
          bf16x8 vf = *(const bf16x8*)(Vc + vrow * 128 + vcs * 16);
          o[nt] = MFMA16(pa, vf, o[nt]);
        }
      }
    }

    __syncthreads();  // drains vmcnt(0): prefetched tile ready; all reads of cur done
    char* tk = Kc; Kc = Kn; Kn = tk;
    char* tv = Vc; Vc = Vn; Vn = tv;
  }

#pragma unroll
  for (int r = 0; r < 4; r++) lrow[r] = 1.f / lrow[r];
  int rowg = b * 2048 + qb * 128 + w * 16 + l4 * 4;
#pragma unroll
  for (int nt = 0; nt < 16; nt++)
#pragma unroll
    for (int r = 0; r < 4; r++)
      AO[(size_t)(rowg + r) * 4096 + h * 256 + nt * 16 + l15] = f2bf(o[nt][r] * lrow[r]);
}

// ---------------- host ----------------

// ws layout (bytes). AO aliases Xb+Wqt (dead by then). Needs 112 MB of ws.
#define OFF_XB   0u
#define OFF_WQT  16777216u
#define OFF_WKT  33554432u
#define OFF_WVT  37748736u
#define OFF_WOT  41943040u
#define OFF_QB   58720256u
#define OFF_KB   92274688u
#define OFF_VB   100663296u
#define OFF_VT   109051904u
#define OFF_AO   0u

extern "C" void kernel_launch(void* const* d_in, const int* in_sizes, int n_in,
                              void* d_out, int out_size, void* d_ws, size_t ws_size,
                              hipStream_t stream) {
  const float* hs = (const float*)d_in[0];
  const int* pos = (const int*)d_in[1];
  const float* wq = (const float*)d_in[2];
  const float* wk = (const float*)d_in[3];
  const float* wv = (const float*)d_in[4];
  const float* wo = (const float*)d_in[5];
  float* out = (float*)d_out;
  char* ws = (char*)d_ws;

  u16* Xb  = (u16*)(ws + OFF_XB);
  u16* Wqt = (u16*)(ws + OFF_WQT);
  u16* Wkt = (u16*)(ws + OFF_WKT);
  u16* Wvt = (u16*)(ws + OFF_WVT);
  u16* Wot = (u16*)(ws + OFF_WOT);
  u16* Qb  = (u16*)(ws + OFF_QB);
  u16* Kb  = (u16*)(ws + OFF_KB);
  u16* Vb  = (u16*)(ws + OFF_VB);
  u16* Vt  = (u16*)(ws + OFF_VT);
  u16* AO  = (u16*)(ws + OFF_AO);

  dim3 tb(32, 8);

  // prep: convert + transposes
  k_convert_f32_bf16<<<8192, 256, 0, stream>>>(hs, Xb, 2097152);
  k_transpose_f32_bf16<<<dim3(128, 64), tb, 0, stream>>>(wq, Wqt, 2048, 4096);
  k_transpose_f32_bf16<<<dim3(32, 64), tb, 0, stream>>>(wk, Wkt, 2048, 1024);
  k_transpose_f32_bf16<<<dim3(32, 64), tb, 0, stream>>>(wv, Wvt, 2048, 1024);
  k_transpose_f32_bf16<<<dim3(64, 128), tb, 0, stream>>>(wo, Wot, 4096, 2048);

  // QKV projections
  k_gemm_bt<1><<<dim3(32, 32), 256, 0, stream>>>(Xb, Wqt, Qb, 4096, 4096, 2048);
  k_gemm_bt<1><<<dim3(8, 32), 256, 0, stream>>>(Xb, Wkt, Kb, 4096, 1024, 2048);
  k_gemm_bt<1><<<dim3(8, 32), 256, 0, stream>>>(Xb, Wvt, Vb, 4096, 1024, 2048);

  // RoPE on Q and K
  k_rope<<<32768, 256, 0, stream>>>(Qb, pos, 15, 4, 4096);
  k_rope<<<8192, 256, 0, stream>>>(Kb, pos, 3, 2, 1024);

  // V^T for attention PV operand
  k_transpose_bf16<<<dim3(32, 128), tb, 0, stream>>>(Vb, Vt, 4096, 1024);

  // flash attention: 512 threads, 144 KB dynamic LDS
  (void)hipFuncSetAttribute((const void*)k_attn, hipFuncAttributeMaxDynamicSharedMemorySize, 147456);
  k_attn<<<dim3(16, 32), 512, 147456, stream>>>(Qb, Kb, Vt, AO);

  // output projection (fp32 out)
  k_gemm_bt<0><<<dim3(16, 32), 256, 0, stream>>>(AO, Wot, out, 4096, 2048, 4096);
}